// Round 8
// baseline (411.477 us; speedup 1.0000x reference)
//
#include <hip/hip_runtime.h>
#include <math.h>

#define HW   56
#define DIMC 256
#define HID  1024

typedef __attribute__((ext_vector_type(8))) short bf16x8;
typedef __attribute__((ext_vector_type(4))) float f32x4;

__device__ __forceinline__ short f2bf(float f) {
  union { float fv; unsigned u; } v; v.fv = f;
  unsigned r = v.u + 0x7fffu + ((v.u >> 16) & 1u);
  return (short)(r >> 16);
}
__device__ __forceinline__ float bf2f(short s) {
  union { unsigned u; float fv; } v; v.u = ((unsigned)(unsigned short)s) << 16;
  return v.fv;
}
// gelu via sigmoid: v*sigmoid(1.702v). rcp (1-ulp approx) fine: error scaled
// by gamma=1e-6 before reaching the output.
__device__ __forceinline__ float gelu_fast(float v) {
  float e = exp2f(-2.4556260f * v);
  return v * __builtin_amdgcn_rcpf(1.f + e);
}
// pack 8 f32 -> 8 OCP e4m3 bytes in one i64 (byte j = value j; A and B use the
// same j-indexing so any HW k-permutation within the 8-group cancels in MFMA).
__device__ __forceinline__ long pk8(float f0, float f1, float f2, float f3,
                                    float f4, float f5, float f6, float f7) {
  int lo = __builtin_amdgcn_cvt_pk_fp8_f32(f0, f1, 0, false);
  lo = __builtin_amdgcn_cvt_pk_fp8_f32(f2, f3, lo, true);
  int hi = __builtin_amdgcn_cvt_pk_fp8_f32(f4, f5, 0, false);
  hi = __builtin_amdgcn_cvt_pk_fp8_f32(f6, f7, hi, true);
  return ((long)(unsigned)lo) | ((long)hi << 32);
}
__device__ __forceinline__ char f2fp8(float f) {
  return (char)(__builtin_amdgcn_cvt_pk_fp8_f32(f, f, 0, false) & 0xff);
}

// ---------------------------------------------------------------------------
// prep_pack: weights -> fp8 MFMA-fragment-major (frag = 64 lanes x 8B = 512B).
// Thread g==0 also zeroes the work-queue counters (re-zeroed every launch).
// ---------------------------------------------------------------------------
__global__ void prep_pack(const float* __restrict__ w1, const float* __restrict__ w2,
                          long* __restrict__ w1p, long* __restrict__ w2p,
                          int* __restrict__ qmeta) {
  int g = blockIdx.x * 256 + threadIdx.x;
  if (g == 0) { qmeta[0] = 0; qmeta[1] = 0; qmeta[2] = 0; }
  int f = g >> 6, lane = g & 63;
  int l15 = lane & 15, q = lane >> 4;
  float t[8];
  if (f < 512) {
    int k8 = f & 7, tt = f >> 3, nt = tt & 1, ch = tt >> 1;
    int n = ch * 32 + nt * 16 + l15;
    int k = k8 * 32 + q * 8;
    #pragma unroll
    for (int j = 0; j < 8; ++j) t[j] = w1[(k + j) * HID + n];
    w1p[f * 64 + lane] = pk8(t[0], t[1], t[2], t[3], t[4], t[5], t[6], t[7]);
  } else {
    int f2 = f - 512;
    int nt2 = f2 & 15, ch = f2 >> 4;
    int k = ch * 32 + q * 8;
    int c = nt2 * 16 + l15;
    #pragma unroll
    for (int j = 0; j < 8; ++j) t[j] = w2[(k + j) * DIMC + c];
    w2p[f2 * 64 + lane] = pk8(t[0], t[1], t[2], t[3], t[4], t[5], t[6], t[7]);
  }
}

// ---------------------------------------------------------------------------
// compact_k: dense active-tile list. qmeta[0]=count, [1]=mlp head, list at +16.
// ---------------------------------------------------------------------------
__global__ void compact_k(const int* __restrict__ mask, int* __restrict__ qmeta) {
  int t = blockIdx.x * 256 + threadIdx.x;
  if (t < 1568 && mask[t]) {
    int i = atomicAdd(qmeta, 1);
    qmeta[16 + i] = t;
  }
}

// ---------------------------------------------------------------------------
// conv_k v5: persistent 8-plane blocks + DOUBLE-BUFFERED staging (T14).
// Block owns 8 consecutive c-planes of one image b (b = bid>>5 fixed -> mask
// bits computed once). Loads for plane n+1 issued into regs at top of
// compute(n); after sync they are ds_written to buf[(n+1)&1] and plane n+2
// loads issued -> HBM latency hides under the ~5500cyc compute. R5 analysis:
// per-block serial {stage-latency + compute} with only 4 blocks/CU cover was
// the 4x gap to the 20us floor. LDS 2x15872+7168 = 38912B -> 4 blocks/CU.
// ---------------------------------------------------------------------------
__global__ __launch_bounds__(256, 4) void conv_k(
    const float* __restrict__ x, const int* __restrict__ mask,
    const float* __restrict__ dw_w, const float* __restrict__ dw_b,
    short* __restrict__ ybuf) {
  __shared__ __align__(16) float s_plane[2][62 * 64];     // 31744 B
  __shared__ __align__(16) short s_out[56 * 64];          // 7168 B

  int tid = threadIdx.x;
  int bid = blockIdx.x;
  int b = bid >> 5;                     // 32 blocks per image
  int c0 = (bid & 31) * 8;              // planes c0..c0+7

  // staging geometry (4 slots/thread; slot<992 exists in LDS, sok loads x)
  int srow[4], sjj[4]; bool sv[4], sok[4];
  #pragma unroll
  for (int it = 0; it < 4; ++it) {
    int slot = tid + 256 * it;
    srow[it] = slot >> 4; sjj[it] = slot & 15;
    sv[it] = slot < 992;
    sok[it] = sv[it] && (srow[it] >= 3) && (srow[it] < 59) && (sjj[it] >= 1) && (sjj[it] <= 14);
  }

  // mask bits: b fixed for the whole block -> once
  int cp = tid & 31, rg = tid >> 5;
  int col0 = cp * 2, wb = col0 >> 3, r0 = rg * 7;
  int mrow = 0;
  if (cp < 28) {
    #pragma unroll
    for (int hb = 0; hb < 7; ++hb)
      mrow |= (mask[(b * 7 + hb) * 7 + wb] ? 1 : 0) << hb;
  }
  int hb1 = r0 >> 3, hb2 = (r0 + 6) >> 3;
  bool anyrow = (cp < 28) && (mrow & ((2 << hb2) - (1 << hb1)));

#define LOADP(CC, R) do {                                                     \
    const float* _xp = x + (long)(b * DIMC + (CC)) * HW * HW;                 \
    _Pragma("unroll")                                                         \
    for (int _it = 0; _it < 4; ++_it) {                                       \
      f32x4 _v = (f32x4){0.f, 0.f, 0.f, 0.f};                                 \
      if (sok[_it])                                                           \
        _v = *(const f32x4*)(_xp + (srow[_it] - 3) * HW + (sjj[_it] * 4 - 4));\
      (R)[_it] = _v;                                                          \
    } } while (0)
#define WRITEP(BUF, R) do {                                                   \
    _Pragma("unroll")                                                         \
    for (int _it = 0; _it < 4; ++_it)                                         \
      if (sv[_it])                                                            \
        *(f32x4*)(&s_plane[BUF][srow[_it] * 64 + sjj[_it] * 4]) = (R)[_it];   \
    } while (0)

  f32x4 r[4];
  LOADP(c0, r);
  WRITEP(0, r);
  LOADP(c0 + 1, r);
  __syncthreads();

  for (int pi = 0; pi < 8; ++pi) {
    int c = c0 + pi;
    const float* sp = &s_plane[pi & 1][0];

    // weights -> SGPRs (uniform per plane)
    float wt[49];
    #pragma unroll
    for (int j = 0; j < 49; ++j) {
      int wi = __builtin_amdgcn_readfirstlane(__builtin_bit_cast(int, dw_w[c * 49 + j]));
      wt[j] = __builtin_bit_cast(float, wi);
    }
    float db = dw_b[c];

    if (anyrow) {
      float W[7][10];                   // rolling window, static idx
#define LDROW(S, LR) do { int _o = (LR) * 64 + col0;                          \
      W[S][0] = sp[_o + 0]; W[S][1] = sp[_o + 1];                             \
      W[S][2] = sp[_o + 2]; W[S][3] = sp[_o + 3];                             \
      W[S][4] = sp[_o + 4]; W[S][5] = sp[_o + 5];                             \
      W[S][6] = sp[_o + 6]; W[S][7] = sp[_o + 7];                             \
      W[S][8] = sp[_o + 8]; W[S][9] = sp[_o + 9]; } while (0)
      LDROW(0, r0 + 0); LDROW(1, r0 + 1); LDROW(2, r0 + 2);
      LDROW(3, r0 + 3); LDROW(4, r0 + 4); LDROW(5, r0 + 5);
      #pragma unroll
      for (int k = 0; k < 7; ++k) {
        LDROW((6 + k) % 7, r0 + 6 + k);
        int rr = r0 + k;
        if ((mrow >> (rr >> 3)) & 1) {
          float out0 = 0.f, out1 = 0.f;
          #pragma unroll
          for (int dy = 0; dy < 7; ++dy) {
            const float* wr = wt + dy * 7;
            const float* ww = W[(k + dy) % 7];
            #pragma unroll
            for (int dx = 0; dx < 7; ++dx) {
              out0 += wr[dx] * ww[1 + dx];
              out1 += wr[dx] * ww[2 + dx];
            }
          }
          unsigned pk = (unsigned)(unsigned short)f2bf(out0 + db)
                      | ((unsigned)(unsigned short)f2bf(out1 + db) << 16);
          ((int*)s_out)[rr * 32 + cp] = (int)pk;
        }
      }
#undef LDROW
    }
    __syncthreads();                    // compute reads of sp / writes of s_out done

    // dump s_out -> ybuf (active tiles only)
    #pragma unroll
    for (int it = 0; it < 2; ++it) {
      int u = tid + 256 * it;
      if (u < 392) {
        int hh = u & 7, th = u >> 3;
        int hbL = th / 7, wbL = th % 7;
        int tile = (b * 7 + hbL) * 7 + wbL;
        if (mask[tile]) {
          bf16x8 v = *(const bf16x8*)(s_out + (hbL * 8 + hh) * 64 + wbL * 8);
          *(bf16x8*)(ybuf + ((long)tile * DIMC + c) * 64 + hh * 8) = v;
        }
      }
    }
    if (pi < 7) {
      WRITEP((pi + 1) & 1, r);          // vmcnt auto-waits on plane pi+1 loads
      if (pi < 6) LOADP(c0 + pi + 2, r);
    }
    __syncthreads();                    // buf[(pi+1)&1] visible; s_out reusable
  }
#undef LOADP
#undef WRITEP
}

// ---------------------------------------------------------------------------
// mlp_k v6 (REVERTED to R5's 99us version): R1's per-tile body (fp8 MFMA, LDS
// bf16 staging transpose, vectorized LN) in a persistent work-queue loop.
// ---------------------------------------------------------------------------
__global__ __launch_bounds__(256, 3) void mlp_k(
    const float* __restrict__ ln_w, const float* __restrict__ ln_b,
    const float* __restrict__ b1v, const float* __restrict__ b2v,
    const float* __restrict__ gammav,
    const long* __restrict__ w1p, const long* __restrict__ w2p,
    int* __restrict__ qmeta, short* __restrict__ ybuf) {
  __shared__ __align__(16) char smem[46592];
  __shared__ int s_u;
  short* s_a   = (short*)smem;                  // [p 64][264] bf16 (LN'd A)
  short* s_del = (short*)smem;                  // alias: [c 256][72] bf16
  char*  s_h8  = smem + 36864;                  // 2 x [64 m][40] fp8
  float* s_p1  = (float*)(smem + 41984);
  float* s_p2  = (float*)(smem + 43008);
  float* s_mu  = (float*)(smem + 44032);
  float* s_rs  = (float*)(smem + 44288);
  float* s_lnw = (float*)(smem + 44544);
  float* s_lnb = (float*)(smem + 45568);

  const int* list = qmeta + 16;
  int tid = threadIdx.x;
  int total = qmeta[0];

  s_lnw[tid] = ln_w[tid];
  s_lnb[tid] = ln_b[tid];

  const int wv = tid >> 6, lane = tid & 63;
  const int l15 = lane & 15, q = lane >> 4;
  const int mh = wv & 1, nh = wv >> 1;          // GEMM1: 2M x 2N wave split

  for (;;) {
    if (tid == 0) s_u = atomicAdd(qmeta + 1, 1);
    __syncthreads();                            // also covers s_lnw/prev-iter
    int i = s_u;
    if (i >= total) break;
    int tile = list[i];
    short* ytile = ybuf + (long)tile * DIMC * 64;

    // load ybuf [c][p] -> transpose into s_a [p][c]
    #pragma unroll
    for (int k = 0; k < 8; ++k) {
      int q4 = tid + 256 * k;
      int c = q4 & 255, pd = (q4 >> 8) * 8;
      bf16x8 v = *(const bf16x8*)(ytile + c * 64 + pd);
      #pragma unroll
      for (int j = 0; j < 8; ++j) s_a[(pd + j) * 264 + c] = v[j];
    }
    __syncthreads();

    // LN stats via vector reads, values kept in registers for the normalize
    {
      int p = tid & 63, cq = tid >> 6;
      bf16x8 va[8];
      float s1 = 0.f, s2 = 0.f;
      #pragma unroll
      for (int ii = 0; ii < 8; ++ii) {
        va[ii] = *(const bf16x8*)(s_a + p * 264 + cq * 64 + ii * 8);
        #pragma unroll
        for (int j = 0; j < 8; ++j) {
          float f = bf2f(va[ii][j]);
          s1 += f; s2 += f * f;
        }
      }
      s_p1[cq * 64 + p] = s1; s_p2[cq * 64 + p] = s2;
      __syncthreads();
      if (tid < 64) {
        float t1 = s_p1[tid] + s_p1[64 + tid] + s_p1[128 + tid] + s_p1[192 + tid];
        float t2 = s_p2[tid] + s_p2[64 + tid] + s_p2[128 + tid] + s_p2[192 + tid];
        float mu = t1 * (1.f / 256.f);
        float var = t2 * (1.f / 256.f) - mu * mu;
        s_mu[tid] = mu; s_rs[tid] = rsqrtf(var + 1e-6f);
      }
      __syncthreads();
      float mu = s_mu[p], rs = s_rs[p];
      #pragma unroll
      for (int ii = 0; ii < 8; ++ii) {
        int c0 = cq * 64 + ii * 8;
        bf16x8 v = va[ii];
        #pragma unroll
        for (int j = 0; j < 8; ++j)
          v[j] = f2bf((bf2f(v[j]) - mu) * rs * s_lnw[c0 + j] + s_lnb[c0 + j]);
        *(bf16x8*)(s_a + p * 264 + c0) = v;
      }
    }
    __syncthreads();

    // hoist the loop-invariant GEMM1 A-operand into fp8 registers (32 VGPRs)
    const short* aRow0 = s_a + (32 * mh + l15) * 264 + q * 8;
    const short* aRow1 = s_a + (32 * mh + 16 + l15) * 264 + q * 8;
    long a0f[8], a1f[8];
    #pragma unroll
    for (int k8 = 0; k8 < 8; ++k8) {
      bf16x8 v0 = *(const bf16x8*)(aRow0 + k8 * 32);
      bf16x8 v1 = *(const bf16x8*)(aRow1 + k8 * 32);
      a0f[k8] = pk8(bf2f(v0[0]), bf2f(v0[1]), bf2f(v0[2]), bf2f(v0[3]),
                    bf2f(v0[4]), bf2f(v0[5]), bf2f(v0[6]), bf2f(v0[7]));
      a1f[k8] = pk8(bf2f(v1[0]), bf2f(v1[1]), bf2f(v1[2]), bf2f(v1[3]),
                    bf2f(v1[4]), bf2f(v1[5]), bf2f(v1[6]), bf2f(v1[7]));
    }

    f32x4 z[4][4];                              // [jt][Mt], c = wv*64+jt*16+l15
    #pragma unroll
    for (int jt = 0; jt < 4; ++jt)
      #pragma unroll
      for (int Mt = 0; Mt < 4; ++Mt) z[jt][Mt] = (f32x4){0.f, 0.f, 0.f, 0.f};

    long w1r[8];                                // prefetched W1 frags (ch=0)
    #pragma unroll
    for (int k8 = 0; k8 < 8; ++k8)
      w1r[k8] = w1p[(long)(nh * 8 + k8) * 64 + lane];

    for (int ch = 0; ch < 32; ++ch) {
      long w2r[4];
      #pragma unroll
      for (int jt = 0; jt < 4; ++jt)
        w2r[jt] = w2p[(long)(ch * 16 + wv * 4 + jt) * 64 + lane];
      float bb = b1v[ch * 32 + 16 * nh + l15];

      f32x4 acc0 = (f32x4){0.f, 0.f, 0.f, 0.f};
      f32x4 acc1 = (f32x4){0.f, 0.f, 0.f, 0.f};
      __builtin_amdgcn_s_setprio(1);
      #pragma unroll
      for (int k8 = 0; k8 < 8; ++k8) {
        acc0 = __builtin_amdgcn_mfma_f32_16x16x32_fp8_fp8(a0f[k8], w1r[k8], acc0, 0, 0, 0);
        acc1 = __builtin_amdgcn_mfma_f32_16x16x32_fp8_fp8(a1f[k8], w1r[k8], acc1, 0, 0, 0);
      }
      __builtin_amdgcn_s_setprio(0);
      long w1n[8];                              // prefetch next chunk's W1
      if (ch < 31) {
        #pragma unroll
        for (int k8 = 0; k8 < 8; ++k8)
          w1n[k8] = w1p[(long)(((ch + 1) * 2 + nh) * 8 + k8) * 64 + lane];
      }
      char* hb = s_h8 + (ch & 1) * 2560;
      #pragma unroll
      for (int r = 0; r < 4; ++r) {
        hb[(32 * mh + 4 * q + r) * 40 + 16 * nh + l15]      = f2fp8(gelu_fast(acc0[r] + bb));
        hb[(32 * mh + 16 + 4 * q + r) * 40 + 16 * nh + l15] = f2fp8(gelu_fast(acc1[r] + bb));
      }
      __syncthreads();                          // h[ch&1] complete
      __builtin_amdgcn_s_setprio(1);
      #pragma unroll
      for (int Mt = 0; Mt < 4; ++Mt) {
        long aH = *(const long*)(hb + (16 * Mt + l15) * 40 + q * 8);
        #pragma unroll
        for (int jt = 0; jt < 4; ++jt)
          z[jt][Mt] = __builtin_amdgcn_mfma_f32_16x16x32_fp8_fp8(aH, w2r[jt], z[jt][Mt], 0, 0, 0);
      }
      __builtin_amdgcn_s_setprio(0);
      if (ch < 31) {
        #pragma unroll
        for (int k8 = 0; k8 < 8; ++k8) w1r[k8] = w1n[k8];
      }
    }

    // epilogue: delta = (z+b2)*gamma -> s_del [c][72] -> ybuf in place
    #pragma unroll
    for (int jt = 0; jt < 4; ++jt) {
      int c = wv * 64 + jt * 16 + l15;
      float bb = b2v[c], gm = gammav[c];
      #pragma unroll
      for (int Mt = 0; Mt < 4; ++Mt) {
        #pragma unroll
        for (int r = 0; r < 4; ++r)
          s_del[c * 72 + 16 * Mt + 4 * q + r] = f2bf((z[jt][Mt][r] + bb) * gm);
      }
    }
    __syncthreads();
    #pragma unroll
    for (int k = 0; k < 8; ++k) {
      int q4 = tid + 256 * k;
      int c = q4 & 255, pd = (q4 >> 8) * 8;
      bf16x8 v = *(const bf16x8*)(s_del + c * 72 + pd);
      *(bf16x8*)(ytile + c * 64 + pd) = v;
    }
    __syncthreads();                            // s_del reads done before next
  }
}

// ---------------------------------------------------------------------------
// epi_k: dense, fully coalesced. out = x + (active ? delta : 0).
// ---------------------------------------------------------------------------
__global__ __launch_bounds__(256) void epi_k(
    const float* __restrict__ x, const int* __restrict__ mask,
    const short* __restrict__ delta, float* __restrict__ out) {
  const int NU = 32 * DIMC * HW * 7;            // units of 8 floats
  int stride = gridDim.x * 256;
  for (int u = blockIdx.x * 256 + threadIdx.x; u < NU; u += stride) {
    int wb = u % 7; int t1 = u / 7;
    int h = t1 % 56; int t2 = t1 / 56;
    int c = t2 & 255; int b = t2 >> 8;
    int g = ((b * DIMC + c) * HW + h) * HW + wb * 8;
    f32x4 x0 = *(const f32x4*)(x + g);
    f32x4 x1 = *(const f32x4*)(x + g + 4);
    int tile = (b * 7 + (h >> 3)) * 7 + wb;
    if (mask[tile]) {
      bf16x8 d = *(const bf16x8*)(delta + ((long)tile * DIMC + c) * 64 + (h & 7) * 8);
      #pragma unroll
      for (int i = 0; i < 4; ++i) { x0[i] += bf2f(d[i]); x1[i] += bf2f(d[4 + i]); }
    }
    *(f32x4*)(out + g) = x0;
    *(f32x4*)(out + g + 4) = x1;
  }
}

extern "C" void kernel_launch(void* const* d_in, const int* in_sizes, int n_in,
                              void* d_out, int out_size, void* d_ws, size_t ws_size,
                              hipStream_t stream) {
  const float* x    = (const float*)d_in[0];
  const int*   mask = (const int*)d_in[1];
  const float* dw_w = (const float*)d_in[2];
  const float* dw_b = (const float*)d_in[3];
  const float* ln_w = (const float*)d_in[4];
  const float* ln_b = (const float*)d_in[5];
  const float* w1   = (const float*)d_in[6];
  const float* b1   = (const float*)d_in[7];
  const float* w2   = (const float*)d_in[8];
  const float* b2   = (const float*)d_in[9];
  const float* gm   = (const float*)d_in[10];
  float* out = (float*)d_out;

  long* w1p  = (long*)d_ws;                     // 256 KB (512 frags x 512B)
  long* w2p  = w1p + 512 * 64;                  // 256 KB
  int*  qmeta = (int*)(w2p + 512 * 64);         // 8 KB: counters + tile list
  short* ybuf = (short*)((char*)qmeta + 8192);  // 51.4 MB

  prep_pack<<<256, 256, 0, stream>>>(w1, w2, w1p, w2p, qmeta);
  compact_k<<<7, 256, 0, stream>>>(mask, qmeta);
  conv_k<<<1024, 256, 0, stream>>>(x, mask, dw_w, dw_b, ybuf);
  mlp_k<<<768, 256, 0, stream>>>(ln_w, ln_b, b1, b2, gm, w1p, w2p, qmeta, ybuf);
  epi_k<<<4096, 256, 0, stream>>>(x, mask, ybuf, out);
}

// Round 9
// 344.799 us; speedup vs baseline: 1.1934x; 1.1934x over previous
//
#include <hip/hip_runtime.h>
#include <math.h>

#define HW   56
#define DIMC 256
#define HID  1024

typedef __attribute__((ext_vector_type(8))) short bf16x8;
typedef __attribute__((ext_vector_type(4))) float f32x4;

__device__ __forceinline__ short f2bf(float f) {
  union { float fv; unsigned u; } v; v.fv = f;
  unsigned r = v.u + 0x7fffu + ((v.u >> 16) & 1u);
  return (short)(r >> 16);
}
__device__ __forceinline__ float bf2f(short s) {
  union { unsigned u; float fv; } v; v.u = ((unsigned)(unsigned short)s) << 16;
  return v.fv;
}
// gelu via sigmoid: v*sigmoid(1.702v). rcp (1-ulp approx) fine: error scaled
// by gamma=1e-6 before reaching the output.
__device__ __forceinline__ float gelu_fast(float v) {
  float e = exp2f(-2.4556260f * v);
  return v * __builtin_amdgcn_rcpf(1.f + e);
}
// pack 8 f32 -> 8 OCP e4m3 bytes in one i64 (byte j = value j; A and B use the
// same j-indexing so any HW k-permutation within the 8-group cancels in MFMA).
__device__ __forceinline__ long pk8(float f0, float f1, float f2, float f3,
                                    float f4, float f5, float f6, float f7) {
  int lo = __builtin_amdgcn_cvt_pk_fp8_f32(f0, f1, 0, false);
  lo = __builtin_amdgcn_cvt_pk_fp8_f32(f2, f3, lo, true);
  int hi = __builtin_amdgcn_cvt_pk_fp8_f32(f4, f5, 0, false);
  hi = __builtin_amdgcn_cvt_pk_fp8_f32(f6, f7, hi, true);
  return ((long)(unsigned)lo) | ((long)hi << 32);
}
__device__ __forceinline__ char f2fp8(float f) {
  return (char)(__builtin_amdgcn_cvt_pk_fp8_f32(f, f, 0, false) & 0xff);
}

// ---------------------------------------------------------------------------
// prep_pack: weights -> fp8 MFMA-fragment-major (frag = 64 lanes x 8B = 512B).
// Block 256 does the active-tile compaction instead (compact_k folded in:
// qmeta[0]=count, [1]=mlp queue head, list at qmeta+16).
// ---------------------------------------------------------------------------
__global__ void prep_pack(const float* __restrict__ w1, const float* __restrict__ w2,
                          const int* __restrict__ mask,
                          long* __restrict__ w1p, long* __restrict__ w2p,
                          int* __restrict__ qmeta) {
  if (blockIdx.x == 256) {
    if (threadIdx.x == 0) { qmeta[0] = 0; qmeta[1] = 0; qmeta[2] = 0; }
    __syncthreads();
    for (int t = threadIdx.x; t < 1568; t += 256)
      if (mask[t]) {
        int i = atomicAdd(qmeta, 1);
        qmeta[16 + i] = t;
      }
    return;
  }
  int g = blockIdx.x * 256 + threadIdx.x;
  int f = g >> 6, lane = g & 63;
  int l15 = lane & 15, q = lane >> 4;
  float t[8];
  if (f < 512) {
    int k8 = f & 7, tt = f >> 3, nt = tt & 1, ch = tt >> 1;
    int n = ch * 32 + nt * 16 + l15;
    int k = k8 * 32 + q * 8;
    #pragma unroll
    for (int j = 0; j < 8; ++j) t[j] = w1[(k + j) * HID + n];
    w1p[f * 64 + lane] = pk8(t[0], t[1], t[2], t[3], t[4], t[5], t[6], t[7]);
  } else {
    int f2 = f - 512;
    int nt2 = f2 & 15, ch = f2 >> 4;
    int k = ch * 32 + q * 8;
    int c = nt2 * 16 + l15;
    #pragma unroll
    for (int j = 0; j < 8; ++j) t[j] = w2[(k + j) * DIMC + c];
    w2p[f2 * 64 + lane] = pk8(t[0], t[1], t[2], t[3], t[4], t[5], t[6], t[7]);
  }
}

// ---------------------------------------------------------------------------
// conv_k v6: v4 skeleton (dense per-(b,c) plane, x read once, coalesced rows)
// with the inner loop rebuilt for LDS throughput:
//  - plane padded [62][68] f32: row stride 17 quads == 1 mod 8 -> b128 reads
//    spread evenly over banks (v4's [.][64] scalar reads were 4-way conflicted:
//    row stride 256B put every row on the same banks -> est. 63us of LDS time).
//  - 4x4 outputs/thread (196 thr = 14 col-quads x 14 row-quads), accumulate
//    over 10 input rows, 3x ds_read_b128 per row-step: 30 vec reads/thread
//    vs v4's 130 scalar reads.
//  - 4-row x 4-col block always lies in ONE tile -> single mask-bit gate,
//    whole-thread skip (~50% of LDS+FMA skipped).
// LDS 16864+7168 = 24032 B -> 6 blocks/CU; ~60 VGPR, no spill.
// ---------------------------------------------------------------------------
__global__ __launch_bounds__(256, 4) void conv_k(
    const float* __restrict__ x, const int* __restrict__ mask,
    const float* __restrict__ dw_w, const float* __restrict__ dw_b,
    short* __restrict__ ybuf) {
  __shared__ __align__(16) float s_plane[62 * 68];        // 16864 B
  __shared__ __align__(16) short s_out[56 * 64];          // 7168 B

  int bid = blockIdx.x;
  int c = bid & 255, b = bid >> 8;
  int tid = threadIdx.x;
  const float* xp = x + (long)(b * DIMC + c) * HW * HW;

  // stage plane with zero halo: input rows -3..58 -> LDS rows 0..61,
  // input cols -4..63 -> LDS floats 0..67 (col c at float c+4).
  #pragma unroll
  for (int it = 0; it < 5; ++it) {
    int slot = tid + 256 * it;
    if (slot < 1054) {                          // 62 rows x 17 quads
      int row = slot / 17, jj = slot - row * 17;
      f32x4 v = (f32x4){0.f, 0.f, 0.f, 0.f};
      if (row >= 3 && row < 59 && jj >= 1 && jj <= 14)
        v = *(const f32x4*)(xp + (row - 3) * HW + (jj * 4 - 4));
      *(f32x4*)(s_plane + row * 68 + jj * 4) = v;
    }
  }

  // weights -> SGPRs (uniform per block: one channel per block)
  float wt[49];
  #pragma unroll
  for (int j = 0; j < 49; ++j) {
    int wi = __builtin_amdgcn_readfirstlane(__builtin_bit_cast(int, dw_w[c * 49 + j]));
    wt[j] = __builtin_bit_cast(float, wi);
  }
  float db = dw_b[c];
  __syncthreads();

  if (tid < 196) {
    int cg = tid % 14, rq = tid / 14;           // col-quad, row-quad
    int tile = (b * 7 + (rq >> 1)) * 7 + (cg >> 1);
    if (mask[tile]) {
      int R0 = rq * 4, C0 = cg * 4;
      float acc[4][4];
      #pragma unroll
      for (int j = 0; j < 4; ++j)
        #pragma unroll
        for (int i = 0; i < 4; ++i) acc[j][i] = 0.f;

      #pragma unroll
      for (int ri = 0; ri < 10; ++ri) {
        const float* base = s_plane + (R0 + ri) * 68 + C0;
        f32x4 q0 = *(const f32x4*)(base);
        f32x4 q1 = *(const f32x4*)(base + 4);
        f32x4 q2 = *(const f32x4*)(base + 8);
        float row[12] = {q0[0], q0[1], q0[2], q0[3],
                         q1[0], q1[1], q1[2], q1[3],
                         q2[0], q2[1], q2[2], q2[3]};
        #pragma unroll
        for (int j = 0; j < 4; ++j) {
          if (ri >= j && ri <= j + 6) {         // static predicate
            const float* wr = wt + (ri - j) * 7;
            #pragma unroll
            for (int i = 0; i < 4; ++i)
              #pragma unroll
              for (int dx = 0; dx < 7; ++dx)
                acc[j][i] += wr[dx] * row[i + dx + 1];
          }
        }
      }
      #pragma unroll
      for (int j = 0; j < 4; ++j) {
        unsigned lo = (unsigned)(unsigned short)f2bf(acc[j][0] + db)
                    | ((unsigned)(unsigned short)f2bf(acc[j][1] + db) << 16);
        unsigned hi = (unsigned)(unsigned short)f2bf(acc[j][2] + db)
                    | ((unsigned)(unsigned short)f2bf(acc[j][3] + db) << 16);
        long pk = ((long)(unsigned)lo) | ((long)hi << 32);
        *(long*)(s_out + (R0 + j) * 64 + C0) = pk;
      }
    }
  }
  __syncthreads();

  // write active tiles: 49 tiles x 8 rows = 392 bf16x8 units, 128B contiguous
  #pragma unroll
  for (int it = 0; it < 2; ++it) {
    int u = tid + 256 * it;
    if (u < 392) {
      int hh = u & 7, th = u >> 3;
      int hbL = th / 7, wbL = th % 7;
      int tile = (b * 7 + hbL) * 7 + wbL;
      if (mask[tile]) {
        bf16x8 v = *(const bf16x8*)(s_out + (hbL * 8 + hh) * 64 + wbL * 8);
        *(bf16x8*)(ybuf + ((long)tile * DIMC + c) * 64 + hh * 8) = v;
      }
    }
  }
}

// ---------------------------------------------------------------------------
// mlp_k v6 (unchanged, proven 99us): fp8 MFMA, LDS bf16 staging transpose,
// vectorized LN, persistent work-queue loop.
// ---------------------------------------------------------------------------
__global__ __launch_bounds__(256, 3) void mlp_k(
    const float* __restrict__ ln_w, const float* __restrict__ ln_b,
    const float* __restrict__ b1v, const float* __restrict__ b2v,
    const float* __restrict__ gammav,
    const long* __restrict__ w1p, const long* __restrict__ w2p,
    int* __restrict__ qmeta, short* __restrict__ ybuf) {
  __shared__ __align__(16) char smem[46592];
  __shared__ int s_u;
  short* s_a   = (short*)smem;                  // [p 64][264] bf16 (LN'd A)
  short* s_del = (short*)smem;                  // alias: [c 256][72] bf16
  char*  s_h8  = smem + 36864;                  // 2 x [64 m][40] fp8
  float* s_p1  = (float*)(smem + 41984);
  float* s_p2  = (float*)(smem + 43008);
  float* s_mu  = (float*)(smem + 44032);
  float* s_rs  = (float*)(smem + 44288);
  float* s_lnw = (float*)(smem + 44544);
  float* s_lnb = (float*)(smem + 45568);

  const int* list = qmeta + 16;
  int tid = threadIdx.x;
  int total = qmeta[0];

  s_lnw[tid] = ln_w[tid];
  s_lnb[tid] = ln_b[tid];

  const int wv = tid >> 6, lane = tid & 63;
  const int l15 = lane & 15, q = lane >> 4;
  const int mh = wv & 1, nh = wv >> 1;          // GEMM1: 2M x 2N wave split

  for (;;) {
    if (tid == 0) s_u = atomicAdd(qmeta + 1, 1);
    __syncthreads();                            // also covers s_lnw/prev-iter
    int i = s_u;
    if (i >= total) break;
    int tile = list[i];
    short* ytile = ybuf + (long)tile * DIMC * 64;

    // load ybuf [c][p] -> transpose into s_a [p][c]
    #pragma unroll
    for (int k = 0; k < 8; ++k) {
      int q4 = tid + 256 * k;
      int c = q4 & 255, pd = (q4 >> 8) * 8;
      bf16x8 v = *(const bf16x8*)(ytile + c * 64 + pd);
      #pragma unroll
      for (int j = 0; j < 8; ++j) s_a[(pd + j) * 264 + c] = v[j];
    }
    __syncthreads();

    // LN stats via vector reads, values kept in registers for the normalize
    {
      int p = tid & 63, cq = tid >> 6;
      bf16x8 va[8];
      float s1 = 0.f, s2 = 0.f;
      #pragma unroll
      for (int ii = 0; ii < 8; ++ii) {
        va[ii] = *(const bf16x8*)(s_a + p * 264 + cq * 64 + ii * 8);
        #pragma unroll
        for (int j = 0; j < 8; ++j) {
          float f = bf2f(va[ii][j]);
          s1 += f; s2 += f * f;
        }
      }
      s_p1[cq * 64 + p] = s1; s_p2[cq * 64 + p] = s2;
      __syncthreads();
      if (tid < 64) {
        float t1 = s_p1[tid] + s_p1[64 + tid] + s_p1[128 + tid] + s_p1[192 + tid];
        float t2 = s_p2[tid] + s_p2[64 + tid] + s_p2[128 + tid] + s_p2[192 + tid];
        float mu = t1 * (1.f / 256.f);
        float var = t2 * (1.f / 256.f) - mu * mu;
        s_mu[tid] = mu; s_rs[tid] = rsqrtf(var + 1e-6f);
      }
      __syncthreads();
      float mu = s_mu[p], rs = s_rs[p];
      #pragma unroll
      for (int ii = 0; ii < 8; ++ii) {
        int c0 = cq * 64 + ii * 8;
        bf16x8 v = va[ii];
        #pragma unroll
        for (int j = 0; j < 8; ++j)
          v[j] = f2bf((bf2f(v[j]) - mu) * rs * s_lnw[c0 + j] + s_lnb[c0 + j]);
        *(bf16x8*)(s_a + p * 264 + c0) = v;
      }
    }
    __syncthreads();

    // hoist the loop-invariant GEMM1 A-operand into fp8 registers (32 VGPRs)
    const short* aRow0 = s_a + (32 * mh + l15) * 264 + q * 8;
    const short* aRow1 = s_a + (32 * mh + 16 + l15) * 264 + q * 8;
    long a0f[8], a1f[8];
    #pragma unroll
    for (int k8 = 0; k8 < 8; ++k8) {
      bf16x8 v0 = *(const bf16x8*)(aRow0 + k8 * 32);
      bf16x8 v1 = *(const bf16x8*)(aRow1 + k8 * 32);
      a0f[k8] = pk8(bf2f(v0[0]), bf2f(v0[1]), bf2f(v0[2]), bf2f(v0[3]),
                    bf2f(v0[4]), bf2f(v0[5]), bf2f(v0[6]), bf2f(v0[7]));
      a1f[k8] = pk8(bf2f(v1[0]), bf2f(v1[1]), bf2f(v1[2]), bf2f(v1[3]),
                    bf2f(v1[4]), bf2f(v1[5]), bf2f(v1[6]), bf2f(v1[7]));
    }

    f32x4 z[4][4];                              // [jt][Mt], c = wv*64+jt*16+l15
    #pragma unroll
    for (int jt = 0; jt < 4; ++jt)
      #pragma unroll
      for (int Mt = 0; Mt < 4; ++Mt) z[jt][Mt] = (f32x4){0.f, 0.f, 0.f, 0.f};

    long w1r[8];                                // prefetched W1 frags (ch=0)
    #pragma unroll
    for (int k8 = 0; k8 < 8; ++k8)
      w1r[k8] = w1p[(long)(nh * 8 + k8) * 64 + lane];

    for (int ch = 0; ch < 32; ++ch) {
      long w2r[4];
      #pragma unroll
      for (int jt = 0; jt < 4; ++jt)
        w2r[jt] = w2p[(long)(ch * 16 + wv * 4 + jt) * 64 + lane];
      float bb = b1v[ch * 32 + 16 * nh + l15];

      f32x4 acc0 = (f32x4){0.f, 0.f, 0.f, 0.f};
      f32x4 acc1 = (f32x4){0.f, 0.f, 0.f, 0.f};
      __builtin_amdgcn_s_setprio(1);
      #pragma unroll
      for (int k8 = 0; k8 < 8; ++k8) {
        acc0 = __builtin_amdgcn_mfma_f32_16x16x32_fp8_fp8(a0f[k8], w1r[k8], acc0, 0, 0, 0);
        acc1 = __builtin_amdgcn_mfma_f32_16x16x32_fp8_fp8(a1f[k8], w1r[k8], acc1, 0, 0, 0);
      }
      __builtin_amdgcn_s_setprio(0);
      long w1n[8];                              // prefetch next chunk's W1
      if (ch < 31) {
        #pragma unroll
        for (int k8 = 0; k8 < 8; ++k8)
          w1n[k8] = w1p[(long)(((ch + 1) * 2 + nh) * 8 + k8) * 64 + lane];
      }
      char* hb = s_h8 + (ch & 1) * 2560;
      #pragma unroll
      for (int r = 0; r < 4; ++r) {
        hb[(32 * mh + 4 * q + r) * 40 + 16 * nh + l15]      = f2fp8(gelu_fast(acc0[r] + bb));
        hb[(32 * mh + 16 + 4 * q + r) * 40 + 16 * nh + l15] = f2fp8(gelu_fast(acc1[r] + bb));
      }
      __syncthreads();                          // h[ch&1] complete
      __builtin_amdgcn_s_setprio(1);
      #pragma unroll
      for (int Mt = 0; Mt < 4; ++Mt) {
        long aH = *(const long*)(hb + (16 * Mt + l15) * 40 + q * 8);
        #pragma unroll
        for (int jt = 0; jt < 4; ++jt)
          z[jt][Mt] = __builtin_amdgcn_mfma_f32_16x16x32_fp8_fp8(aH, w2r[jt], z[jt][Mt], 0, 0, 0);
      }
      __builtin_amdgcn_s_setprio(0);
      if (ch < 31) {
        #pragma unroll
        for (int k8 = 0; k8 < 8; ++k8) w1r[k8] = w1n[k8];
      }
    }

    // epilogue: delta = (z+b2)*gamma -> s_del [c][72] -> ybuf in place
    #pragma unroll
    for (int jt = 0; jt < 4; ++jt) {
      int c = wv * 64 + jt * 16 + l15;
      float bb = b2v[c], gm = gammav[c];
      #pragma unroll
      for (int Mt = 0; Mt < 4; ++Mt) {
        #pragma unroll
        for (int r = 0; r < 4; ++r)
          s_del[c * 72 + 16 * Mt + 4 * q + r] = f2bf((z[jt][Mt][r] + bb) * gm);
      }
    }
    __syncthreads();
    #pragma unroll
    for (int k = 0; k < 8; ++k) {
      int q4 = tid + 256 * k;
      int c = q4 & 255, pd = (q4 >> 8) * 8;
      bf16x8 v = *(const bf16x8*)(s_del + c * 72 + pd);
      *(bf16x8*)(ytile + c * 64 + pd) = v;
    }
    __syncthreads();                            // s_del reads done before next
  }
}

// ---------------------------------------------------------------------------
// epi_k: dense, fully coalesced. out = x + (active ? delta : 0).
// ---------------------------------------------------------------------------
__global__ __launch_bounds__(256) void epi_k(
    const float* __restrict__ x, const int* __restrict__ mask,
    const short* __restrict__ delta, float* __restrict__ out) {
  const int NU = 32 * DIMC * HW * 7;            // units of 8 floats
  int stride = gridDim.x * 256;
  for (int u = blockIdx.x * 256 + threadIdx.x; u < NU; u += stride) {
    int wb = u % 7; int t1 = u / 7;
    int h = t1 % 56; int t2 = t1 / 56;
    int c = t2 & 255; int b = t2 >> 8;
    int g = ((b * DIMC + c) * HW + h) * HW + wb * 8;
    f32x4 x0 = *(const f32x4*)(x + g);
    f32x4 x1 = *(const f32x4*)(x + g + 4);
    int tile = (b * 7 + (h >> 3)) * 7 + wb;
    if (mask[tile]) {
      bf16x8 d = *(const bf16x8*)(delta + ((long)tile * DIMC + c) * 64 + (h & 7) * 8);
      #pragma unroll
      for (int i = 0; i < 4; ++i) { x0[i] += bf2f(d[i]); x1[i] += bf2f(d[4 + i]); }
    }
    *(f32x4*)(out + g) = x0;
    *(f32x4*)(out + g + 4) = x1;
  }
}

extern "C" void kernel_launch(void* const* d_in, const int* in_sizes, int n_in,
                              void* d_out, int out_size, void* d_ws, size_t ws_size,
                              hipStream_t stream) {
  const float* x    = (const float*)d_in[0];
  const int*   mask = (const int*)d_in[1];
  const float* dw_w = (const float*)d_in[2];
  const float* dw_b = (const float*)d_in[3];
  const float* ln_w = (const float*)d_in[4];
  const float* ln_b = (const float*)d_in[5];
  const float* w1   = (const float*)d_in[6];
  const float* b1   = (const float*)d_in[7];
  const float* w2   = (const float*)d_in[8];
  const float* b2   = (const float*)d_in[9];
  const float* gm   = (const float*)d_in[10];
  float* out = (float*)d_out;

  long* w1p  = (long*)d_ws;                     // 256 KB (512 frags x 512B)
  long* w2p  = w1p + 512 * 64;                  // 256 KB
  int*  qmeta = (int*)(w2p + 512 * 64);         // 8 KB: counters + tile list
  short* ybuf = (short*)((char*)qmeta + 8192);  // 51.4 MB

  prep_pack<<<257, 256, 0, stream>>>(w1, w2, mask, w1p, w2p, qmeta);
  conv_k<<<8192, 256, 0, stream>>>(x, mask, dw_w, dw_b, ybuf);
  mlp_k<<<768, 256, 0, stream>>>(ln_w, ln_b, b1, b2, gm, w1p, w2p, qmeta, ybuf);
  epi_k<<<4096, 256, 0, stream>>>(x, mask, ybuf, out);
}